// Round 2
// baseline (842.776 us; speedup 1.0000x reference)
//
#include <hip/hip_runtime.h>
#include <cstdint>
#include <cstddef>

typedef __bf16 bf16_t;
typedef __bf16 bf16x8 __attribute__((ext_vector_type(8)));
typedef float  f32x4  __attribute__((ext_vector_type(4)));

#define S_LEN   2048
#define E_DIM   512
#define H_NUM   8
#define DH      64
#define MLP_DIM 2048

static __device__ __forceinline__ unsigned short f2bfu(float f){
  bf16_t h = (bf16_t)f;
  return __builtin_bit_cast(unsigned short, h);
}

static __device__ __forceinline__ float gelu_f(float v){
  return 0.5f*v*(1.0f + erff(v*0.70710678118654752f));
}

// ---------------- fp32 -> bf16 convert (plain) ----------------
__global__ __launch_bounds__(256) void cvt_kernel(const float* __restrict__ s,
                                                  bf16_t* __restrict__ d, int n){
  int i = (blockIdx.x*256 + threadIdx.x)*4;
  if (i < n){
    float4 v = *(const float4*)(s + i);
    ushort4 pk;
    pk.x = f2bfu(v.x); pk.y = f2bfu(v.y); pk.z = f2bfu(v.z); pk.w = f2bfu(v.w);
    *(ushort4*)((unsigned short*)d + i) = pk;
  }
}

// ---------------- fp32 -> split (hi+lo) bf16 convert ----------------
__global__ __launch_bounds__(256) void cvt_split_kernel(const float* __restrict__ s,
                                                        bf16_t* __restrict__ dh,
                                                        bf16_t* __restrict__ dl, int n){
  int i = (blockIdx.x*256 + threadIdx.x)*4;
  if (i < n){
    float4 v = *(const float4*)(s + i);
    float xs[4] = {v.x, v.y, v.z, v.w};
    ushort4 ph, pl;
    unsigned short* hp = (unsigned short*)&ph;
    unsigned short* lp = (unsigned short*)&pl;
    #pragma unroll
    for (int j=0;j<4;j++){
      bf16_t hi = (bf16_t)xs[j];
      bf16_t lo = (bf16_t)(xs[j] - (float)hi);
      hp[j] = __builtin_bit_cast(unsigned short, hi);
      lp[j] = __builtin_bit_cast(unsigned short, lo);
    }
    *(ushort4*)((unsigned short*)dh + i) = ph;
    *(ushort4*)((unsigned short*)dl + i) = pl;
  }
}

// ---------------- LayerNorm (plain bf16 out): one wave per row ----------------
__global__ __launch_bounds__(256) void ln_kernel(const float* __restrict__ x,
                                                 const float* __restrict__ w,
                                                 const float* __restrict__ bb,
                                                 bf16_t* __restrict__ out){
  const int row  = blockIdx.x*4 + (threadIdx.x>>6);
  const int lane = threadIdx.x & 63;
  const float* xr = x + (size_t)row*E_DIM + lane*8;
  float4 v0 = *(const float4*)xr;
  float4 v1 = *(const float4*)(xr + 4);
  float xs[8] = {v0.x, v0.y, v0.z, v0.w, v1.x, v1.y, v1.z, v1.w};
  float s = 0.f, s2 = 0.f;
  #pragma unroll
  for (int j=0;j<8;j++){ s += xs[j]; s2 += xs[j]*xs[j]; }
  #pragma unroll
  for (int off=1; off<64; off<<=1){
    s  += __shfl_xor(s,  off, 64);
    s2 += __shfl_xor(s2, off, 64);
  }
  float mean = s*(1.f/512.f);
  float var  = s2*(1.f/512.f) - mean*mean;
  float rstd = rsqrtf(fmaxf(var, 0.f) + 1e-5f);
  const float* wp = w  + lane*8;
  const float* bp = bb + lane*8;
  bf16x8 ov;
  #pragma unroll
  for (int j=0;j<8;j++)
    ov[j] = (bf16_t)((xs[j]-mean)*rstd*wp[j] + bp[j]);
  *(bf16x8*)(out + (size_t)row*E_DIM + lane*8) = ov;
}

// ---------------- LayerNorm with split hi/lo bf16 output ----------------
__global__ __launch_bounds__(256) void ln_split_kernel(const float* __restrict__ x,
                                                       const float* __restrict__ w,
                                                       const float* __restrict__ bb,
                                                       bf16_t* __restrict__ oh,
                                                       bf16_t* __restrict__ ol){
  const int row  = blockIdx.x*4 + (threadIdx.x>>6);
  const int lane = threadIdx.x & 63;
  const float* xr = x + (size_t)row*E_DIM + lane*8;
  float4 v0 = *(const float4*)xr;
  float4 v1 = *(const float4*)(xr + 4);
  float xs[8] = {v0.x, v0.y, v0.z, v0.w, v1.x, v1.y, v1.z, v1.w};
  float s = 0.f, s2 = 0.f;
  #pragma unroll
  for (int j=0;j<8;j++){ s += xs[j]; s2 += xs[j]*xs[j]; }
  #pragma unroll
  for (int off=1; off<64; off<<=1){
    s  += __shfl_xor(s,  off, 64);
    s2 += __shfl_xor(s2, off, 64);
  }
  float mean = s*(1.f/512.f);
  float var  = s2*(1.f/512.f) - mean*mean;
  float rstd = rsqrtf(fmaxf(var, 0.f) + 1e-5f);
  const float* wp = w  + lane*8;
  const float* bp = bb + lane*8;
  bf16x8 vh, vl;
  #pragma unroll
  for (int j=0;j<8;j++){
    float v = (xs[j]-mean)*rstd*wp[j] + bp[j];
    bf16_t hi = (bf16_t)v;
    vh[j] = hi;
    vl[j] = (bf16_t)(v - (float)hi);
  }
  size_t o = (size_t)row*E_DIM + lane*8;
  *(bf16x8*)(oh + o) = vh;
  *(bf16x8*)(ol + o) = vl;
}

// ---------------- split-precision QKV GEMM ----------------
// C = (Ah+Al)(M,K) @ (Bh+Bl)(N,K)^T + bias, 3-term MFMA (hh + lh + hl).
// Epilogue: cols [0,512) -> qh/ql split; [512,1024) -> kh/kl split;
//           [1024,1536) -> v plain bf16 (B,S,E) flat.
__global__ __launch_bounds__(256) void gemm_qkv_split(
    const bf16_t* __restrict__ Ah, const bf16_t* __restrict__ Al,
    const bf16_t* __restrict__ Bh, const bf16_t* __restrict__ Bl,
    const float* __restrict__ bias,
    bf16_t* __restrict__ qh, bf16_t* __restrict__ ql,
    bf16_t* __restrict__ kh, bf16_t* __restrict__ kl,
    bf16_t* __restrict__ vtmp)
{
  constexpr int TM = 128, TN = 64, BK = 64, MI = 4, NI = 2;
  const int K = 512;

  __shared__ bf16_t Ahs[TM*BK], Als[TM*BK];
  __shared__ bf16_t Bhs[TN*BK], Bls[TN*BK];

  const int tid  = threadIdx.x;
  const int wave = tid>>6, lane = tid&63, quad = lane>>4, l16 = lane&15;
  const int wm = wave>>1, wn = wave&1;

  const int nblk = 1536/TN;
  const int bm = blockIdx.x / nblk;
  const int bn = blockIdx.x % nblk;
  const int m0 = bm*TM, n0 = bn*TN;

  f32x4 acc[MI][NI];
  #pragma unroll
  for (int i=0;i<MI;i++)
    #pragma unroll
    for (int j=0;j<NI;j++)
      acc[i][j] = (f32x4){0.f,0.f,0.f,0.f};

  for (int k0 = 0; k0 < K; k0 += BK){
    bf16x8 avh[4], avl[4], bvh[2], bvl[2];
    #pragma unroll
    for (int i=0;i<4;i++){
      int ga = tid + i*256;
      int row = ga>>3, c8 = (ga&7) ^ (row&7);
      size_t off = (size_t)(m0+row)*K + k0 + c8*8;
      avh[i] = *(const bf16x8*)(Ah + off);
      avl[i] = *(const bf16x8*)(Al + off);
    }
    #pragma unroll
    for (int i=0;i<2;i++){
      int gb = tid + i*256;
      int row = gb>>3, c8 = (gb&7) ^ (row&7);
      size_t off = (size_t)(n0+row)*K + k0 + c8*8;
      bvh[i] = *(const bf16x8*)(Bh + off);
      bvl[i] = *(const bf16x8*)(Bl + off);
    }
    __syncthreads();
    #pragma unroll
    for (int i=0;i<4;i++){
      *(bf16x8*)(Ahs + (size_t)(tid + i*256)*8) = avh[i];
      *(bf16x8*)(Als + (size_t)(tid + i*256)*8) = avl[i];
    }
    #pragma unroll
    for (int i=0;i<2;i++){
      *(bf16x8*)(Bhs + (size_t)(tid + i*256)*8) = bvh[i];
      *(bf16x8*)(Bls + (size_t)(tid + i*256)*8) = bvl[i];
    }
    __syncthreads();
    #pragma unroll
    for (int ks=0;ks<2;ks++){
      bf16x8 afh[MI], afl[MI], bfh[NI], bfl[NI];
      #pragma unroll
      for (int mi=0;mi<MI;mi++){
        int rm = wm*64 + mi*16 + l16;
        size_t sl = (size_t)(rm*8 + ((ks*4+quad) ^ (rm&7)))*8;
        afh[mi] = *(const bf16x8*)(Ahs + sl);
        afl[mi] = *(const bf16x8*)(Als + sl);
      }
      #pragma unroll
      for (int ni=0;ni<NI;ni++){
        int rn = wn*32 + ni*16 + l16;
        size_t sl = (size_t)(rn*8 + ((ks*4+quad) ^ (rn&7)))*8;
        bfh[ni] = *(const bf16x8*)(Bhs + sl);
        bfl[ni] = *(const bf16x8*)(Bls + sl);
      }
      #pragma unroll
      for (int mi=0;mi<MI;mi++)
        #pragma unroll
        for (int ni=0;ni<NI;ni++){
          acc[mi][ni] = __builtin_amdgcn_mfma_f32_16x16x32_bf16(afh[mi], bfh[ni], acc[mi][ni], 0,0,0);
          acc[mi][ni] = __builtin_amdgcn_mfma_f32_16x16x32_bf16(afl[mi], bfh[ni], acc[mi][ni], 0,0,0);
          acc[mi][ni] = __builtin_amdgcn_mfma_f32_16x16x32_bf16(afh[mi], bfl[ni], acc[mi][ni], 0,0,0);
        }
    }
  }

  #pragma unroll
  for (int mi=0;mi<MI;mi++){
    const int grow0 = m0 + wm*64 + mi*16 + quad*4;
    #pragma unroll
    for (int ni=0;ni<NI;ni++){
      const int gcol = n0 + wn*32 + ni*16 + l16;
      const float bvx = bias[gcol];
      if (gcol < 512){
        #pragma unroll
        for (int r=0;r<4;r++){
          float v = acc[mi][ni][r] + bvx;
          size_t idx = (size_t)(grow0+r)*E_DIM + gcol;
          bf16_t hi = (bf16_t)v;
          qh[idx] = hi;
          ql[idx] = (bf16_t)(v - (float)hi);
        }
      } else if (gcol < 1024){
        const int cc = gcol - 512;
        #pragma unroll
        for (int r=0;r<4;r++){
          float v = acc[mi][ni][r] + bvx;
          size_t idx = (size_t)(grow0+r)*E_DIM + cc;
          bf16_t hi = (bf16_t)v;
          kh[idx] = hi;
          kl[idx] = (bf16_t)(v - (float)hi);
        }
      } else {
        const int cc = gcol - 1024;
        #pragma unroll
        for (int r=0;r<4;r++)
          vtmp[(size_t)(grow0+r)*E_DIM + cc] = (bf16_t)(acc[mi][ni][r] + bvx);
      }
    }
  }
}

// ---------------- V transpose: (B,S,E) flat -> vt[i][d][t] ----------------
// Raw-reshape pseudo-tensor: v~[i][t][d] = v_flat[i*131072 + t*64 + d]
// (i = row//256, t = (row%256)*8 + e//64, d = e%64). vt has t innermost.
__global__ __launch_bounds__(256) void vtrans_kernel(const bf16_t* __restrict__ v,
                                                     bf16_t* __restrict__ vt){
  __shared__ bf16_t tile[32*516];   // pitch 516 -> conflict-free strided reads
  const int ic = blockIdx.x >> 3;   // chunk [0,16)
  const int rg = blockIdx.x & 7;    // 32-row group within chunk
  const int tid = threadIdx.x;
  const size_t src = ((size_t)ic*256 + rg*32)*E_DIM;
  #pragma unroll
  for (int j=0;j<8;j++){
    int idx = j*2048 + tid*8;
    int row = idx >> 9, col = idx & 511;
    *(bf16x8*)(tile + row*516 + col) = *(const bf16x8*)(v + src + idx);
  }
  __syncthreads();
  #pragma unroll
  for (int j=0;j<8;j++){
    int idx = j*2048 + tid*8;
    int d = idx >> 8;               // [0,64)
    int toff = idx & 255;           // multiple of 8
    int row = toff >> 3;
    bf16x8 o;
    #pragma unroll
    for (int jj=0;jj<8;jj++)
      o[jj] = tile[row*516 + jj*64 + d];
    *(bf16x8*)(vt + ((size_t)ic*64 + d)*S_LEN + rg*256 + toff) = o;
  }
}

// ---------------- plain bf16 GEMM: C = A(M,K) @ Bw(N,K)^T + bias ----------------
// MODE 1: out = resid + acc + bias -> fp32
// MODE 2: out = gelu(acc+bias) -> bf16
// MODE 3: out += acc + bias (fp32 RMW)
template<int TN, int MODE>
__global__ __launch_bounds__(256) void gemm_kernel(
    const bf16_t* __restrict__ A, const bf16_t* __restrict__ Bw,
    const float* __restrict__ bias, int M, int N, int K,
    void* out0, const float* __restrict__ resid)
{
  constexpr int TM = 128;
  constexpr int BK = 64;
  constexpr int MI = 4;
  constexpr int NI = TN/32;
  constexpr int GB = TN/32;

  __shared__ bf16_t As[TM*BK];
  __shared__ bf16_t Bs[TN*BK];

  const int tid  = threadIdx.x;
  const int wave = tid>>6, lane = tid&63, quad = lane>>4, l16 = lane&15;
  const int wm = wave>>1, wn = wave&1;

  const int nblk = N / TN;
  const int bm = blockIdx.x / nblk;
  const int bn = blockIdx.x % nblk;
  const int m0 = bm*TM, n0 = bn*TN;

  f32x4 acc[MI][NI];
  #pragma unroll
  for (int i=0;i<MI;i++)
    #pragma unroll
    for (int j=0;j<NI;j++)
      acc[i][j] = (f32x4){0.f,0.f,0.f,0.f};

  for (int k0 = 0; k0 < K; k0 += BK){
    bf16x8 av[4];
    #pragma unroll
    for (int i=0;i<4;i++){
      int ga = tid + i*256;
      int row = ga>>3, c8 = (ga&7) ^ (row&7);
      av[i] = *(const bf16x8*)(A + (size_t)(m0+row)*K + k0 + c8*8);
    }
    bf16x8 bv[GB];
    #pragma unroll
    for (int i=0;i<GB;i++){
      int gb = tid + i*256;
      int row = gb>>3, c8 = (gb&7) ^ (row&7);
      bv[i] = *(const bf16x8*)(Bw + (size_t)(n0+row)*K + k0 + c8*8);
    }
    __syncthreads();
    #pragma unroll
    for (int i=0;i<4;i++)  *(bf16x8*)(As + (size_t)(tid + i*256)*8) = av[i];
    #pragma unroll
    for (int i=0;i<GB;i++) *(bf16x8*)(Bs + (size_t)(tid + i*256)*8) = bv[i];
    __syncthreads();
    #pragma unroll
    for (int ks=0;ks<2;ks++){
      bf16x8 af[MI], bfr[NI];
      #pragma unroll
      for (int mi=0;mi<MI;mi++){
        int rm = wm*64 + mi*16 + l16;
        af[mi] = *(const bf16x8*)(As + (size_t)(rm*8 + ((ks*4+quad) ^ (rm&7)))*8);
      }
      #pragma unroll
      for (int ni=0;ni<NI;ni++){
        int rn = wn*(TN/2) + ni*16 + l16;
        bfr[ni] = *(const bf16x8*)(Bs + (size_t)(rn*8 + ((ks*4+quad) ^ (rn&7)))*8);
      }
      #pragma unroll
      for (int mi=0;mi<MI;mi++)
        #pragma unroll
        for (int ni=0;ni<NI;ni++)
          acc[mi][ni] = __builtin_amdgcn_mfma_f32_16x16x32_bf16(af[mi], bfr[ni], acc[mi][ni], 0,0,0);
    }
  }

  #pragma unroll
  for (int mi=0;mi<MI;mi++){
    const int grow0 = m0 + wm*64 + mi*16 + quad*4;
    #pragma unroll
    for (int ni=0;ni<NI;ni++){
      const int gcol = n0 + wn*(TN/2) + ni*16 + l16;
      const float bvx = bias[gcol];
      if constexpr (MODE==1){
        float* xo = (float*)out0;
        #pragma unroll
        for (int r=0;r<4;r++){
          size_t idx = (size_t)(grow0+r)*E_DIM + gcol;
          xo[idx] = resid[idx] + acc[mi][ni][r] + bvx;
        }
      } else if constexpr (MODE==2){
        bf16_t* hp = (bf16_t*)out0;
        #pragma unroll
        for (int r=0;r<4;r++)
          hp[(size_t)(grow0+r)*MLP_DIM + gcol] = (bf16_t)gelu_f(acc[mi][ni][r] + bvx);
      } else {
        float* xo = (float*)out0;
        #pragma unroll
        for (int r=0;r<4;r++){
          size_t idx = (size_t)(grow0+r)*E_DIM + gcol;
          xo[idx] = xo[idx] + acc[mi][ni][r] + bvx;
        }
      }
    }
  }
}

// ---------------- fused attention (pseudo-head raw-reshape semantics) ----------------
// One block = (pseudo-head bh, 16 query rows). Gate read once; u = (q.k^T)*gate
// cached in 131KB LDS fp32; fp64 row-sum; renorm + exact softmax + PV + aw atomics.
__global__ __launch_bounds__(512) void attn_kernel(
    const bf16_t* __restrict__ qhb, const bf16_t* __restrict__ qlb,
    const bf16_t* __restrict__ khb, const bf16_t* __restrict__ klb,
    const bf16_t* __restrict__ vt,  const float* __restrict__ gate,
    bf16_t* __restrict__ og, float* __restrict__ aw)
{
  __shared__ float  u_s[16*2052];      // 131328 B
  __shared__ double red_d[8*16];
  __shared__ float  red_m[2*8*16];
  __shared__ float  osh[16*64];
  __shared__ float  zsh[16];
  __shared__ float  invr_sh[16];
  __shared__ float  msh[16];

  // XCD swizzle: all 8 pseudo-heads of one (b, q-tile) on one XCD (aw locality)
  const int bid = blockIdx.x;
  const int c = bid & 7;
  const int t = bid >> 3;
  const int h = t & 7;
  const int g = t >> 3;
  const int gi = g*8 + c;
  const int b  = gi >> 7;
  const int sqt = gi & 127;
  const int bh = b*H_NUM + h;
  const int sq0 = sqt*16;

  const int tid = threadIdx.x;
  const int wave = tid>>6, lane = tid&63, quad = lane>>4, l16 = lane&15;

  for (int i = tid; i < 16*64; i += 512) osh[i] = 0.f;
  if (tid < 16) zsh[tid] = 0.f;

  bf16x8 qah0, qah1, qal0, qal1;
  {
    const size_t qoff = ((size_t)bh*S_LEN + sq0 + l16)*DH + quad*8;
    qah0 = *(const bf16x8*)(qhb + qoff);
    qah1 = *(const bf16x8*)(qhb + qoff + 32);
    qal0 = *(const bf16x8*)(qlb + qoff);
    qal1 = *(const bf16x8*)(qlb + qoff + 32);
  }

  double sums[4] = {0.0,0.0,0.0,0.0};
  float maxs[4], mins[4];
  #pragma unroll
  for (int r=0;r<4;r++){ maxs[r] = -__builtin_inff(); mins[r] = __builtin_inff(); }

  const size_t gate_row = ((size_t)bh*S_LEN + sq0 + quad*4)*S_LEN;

  // ---- pass 1: u = (q.k^T)*gate -> LDS; fp64 row sums; row max/min
  for (int cb = wave; cb < 32; cb += 8){
    #pragma unroll
    for (int nb=0; nb<4; nb++){
      const int col0 = cb*64 + nb*16;
      const size_t koff = ((size_t)bh*S_LEN + col0 + l16)*DH + quad*8;
      bf16x8 khf0 = *(const bf16x8*)(khb + koff);
      bf16x8 khf1 = *(const bf16x8*)(khb + koff + 32);
      bf16x8 klf0 = *(const bf16x8*)(klb + koff);
      bf16x8 klf1 = *(const bf16x8*)(klb + koff + 32);
      const int sk = col0 + l16;
      const float* gp = gate + gate_row + sk;
      float gv[4];
      #pragma unroll
      for (int r=0;r<4;r++) gv[r] = gp[(size_t)r*S_LEN];
      f32x4 acc = (f32x4){0.f,0.f,0.f,0.f};
      acc = __builtin_amdgcn_mfma_f32_16x16x32_bf16(qah0, khf0, acc, 0,0,0);
      acc = __builtin_amdgcn_mfma_f32_16x16x32_bf16(qah1, khf1, acc, 0,0,0);
      acc = __builtin_amdgcn_mfma_f32_16x16x32_bf16(qal0, khf0, acc, 0,0,0);
      acc = __builtin_amdgcn_mfma_f32_16x16x32_bf16(qal1, khf1, acc, 0,0,0);
      acc = __builtin_amdgcn_mfma_f32_16x16x32_bf16(qah0, klf0, acc, 0,0,0);
      acc = __builtin_amdgcn_mfma_f32_16x16x32_bf16(qah1, klf1, acc, 0,0,0);
      #pragma unroll
      for (int r=0;r<4;r++){
        float u = acc[r]*gv[r];
        u_s[(quad*4+r)*2052 + sk] = u;
        sums[r] += (double)u;
        maxs[r] = fmaxf(maxs[r], u);
        mins[r] = fminf(mins[r], u);
      }
    }
  }

  #pragma unroll
  for (int off=1; off<16; off<<=1){
    #pragma unroll
    for (int r=0;r<4;r++){
      sums[r] += __shfl_xor(sums[r], off, 64);
      maxs[r] = fmaxf(maxs[r], __shfl_xor(maxs[r], off, 64));
      mins[r] = fminf(mins[r], __shfl_xor(mins[r], off, 64));
    }
  }
  if (l16 == 0){
    #pragma unroll
    for (int r=0;r<4;r++){
      red_d[wave*16 + quad*4 + r] = sums[r];
      red_m[(0*8 + wave)*16 + quad*4 + r] = maxs[r];
      red_m[(1*8 + wave)*16 + quad*4 + r] = mins[r];
    }
  }
  __syncthreads();
  if (tid < 16){
    double sm = 0.0;
    float mx = -__builtin_inff(), mn = __builtin_inff();
    #pragma unroll
    for (int w=0; w<8; w++){
      sm += red_d[w*16 + tid];
      mx = fmaxf(mx, red_m[(0*8 + w)*16 + tid]);
      mn = fminf(mn, red_m[(1*8 + w)*16 + tid]);
    }
    double rsum = sm + 1e-12;
    float inv = (float)(1.0/rsum);
    invr_sh[tid] = inv;
    msh[tid] = (rsum > 0.0 ? mx : mn) * inv;   // exact max of u*inv -> max e == 1
  }
  __syncthreads();

  // ---- pass 2: e = exp(u*inv - m); z; o = e @ V
  const float inv_r = invr_sh[l16];
  const float m_v   = msh[l16];
  const int nb2 = wave & 3, kh2 = wave >> 2;
  f32x4 oacc = (f32x4){0.f,0.f,0.f,0.f};
  float zp = 0.f;
  const bf16_t* vbase = vt + ((size_t)bh*DH + nb2*16 + l16)*S_LEN;
  const float* urow = &u_s[l16*2052];
  for (int kc = kh2*32; kc < kh2*32 + 32; kc++){
    const int k0 = kc*32 + quad*8;
    float4 u0 = *(const float4*)(urow + k0);
    float4 u1 = *(const float4*)(urow + k0 + 4);
    float e0 = __expf(u0.x*inv_r - m_v);
    float e1 = __expf(u0.y*inv_r - m_v);
    float e2 = __expf(u0.z*inv_r - m_v);
    float e3 = __expf(u0.w*inv_r - m_v);
    float e4 = __expf(u1.x*inv_r - m_v);
    float e5 = __expf(u1.y*inv_r - m_v);
    float e6 = __expf(u1.z*inv_r - m_v);
    float e7 = __expf(u1.w*inv_r - m_v);
    if (nb2 == 0) zp += ((e0+e1)+(e2+e3)) + ((e4+e5)+(e6+e7));
    bf16x8 pa;
    pa[0]=(bf16_t)e0; pa[1]=(bf16_t)e1; pa[2]=(bf16_t)e2; pa[3]=(bf16_t)e3;
    pa[4]=(bf16_t)e4; pa[5]=(bf16_t)e5; pa[6]=(bf16_t)e6; pa[7]=(bf16_t)e7;
    bf16x8 vf = *(const bf16x8*)(vbase + k0);
    oacc = __builtin_amdgcn_mfma_f32_16x16x32_bf16(pa, vf, oacc, 0,0,0);
  }
  if (nb2 == 0){
    zp += __shfl_xor(zp, 16, 64);
    zp += __shfl_xor(zp, 32, 64);
    if (lane < 16) atomicAdd(&zsh[l16], zp);
  }
  #pragma unroll
  for (int r=0;r<4;r++)
    atomicAdd(&osh[(quad*4+r)*64 + nb2*16 + l16], oacc[r]);
  __syncthreads();

  // ---- epilogue: o/z gathered to (B, t, E) layout for out-proj
  const int bq = bh >> 3, hh = bh & 7;
  for (int i = tid; i < 16*64; i += 512){
    int r = i >> 6, d = i & 63;
    float val = osh[i] / zsh[r];
    og[((size_t)(bq*S_LEN + sq0 + r))*E_DIM + hh*DH + d] = (bf16_t)val;
  }

  // ---- pass 3: head-mean attention weights (fp32 atomics)
  const int r3 = tid >> 5, g32 = tid & 31;
  const float inv3 = invr_sh[r3], m3 = msh[r3];
  const float sc = 0.125f / zsh[r3];
  float* awrow = aw + ((size_t)(bq*S_LEN) + sq0 + r3)*S_LEN;
  const float* ur3 = &u_s[r3*2052];
  for (int col = g32; col < S_LEN; col += 32){
    float e = __expf(ur3[col]*inv3 - m3);
    atomicAdd(&awrow[col], e*sc);
  }
}

// ---------------- launch ----------------
extern "C" void kernel_launch(void* const* d_in, const int* in_sizes, int n_in,
                              void* d_out, int out_size, void* d_ws, size_t ws_size,
                              hipStream_t stream)
{
  const float* query     = (const float*)d_in[0];
  const float* gate      = (const float*)d_in[1];
  const float* in_proj_w = (const float*)d_in[2];
  const float* in_proj_b = (const float*)d_in[3];
  const float* out_w     = (const float*)d_in[4];
  const float* out_b     = (const float*)d_in[5];
  const float* ln1_w     = (const float*)d_in[6];
  const float* ln1_b     = (const float*)d_in[7];
  const float* ln2_w     = (const float*)d_in[8];
  const float* ln2_b     = (const float*)d_in[9];
  const float* w1        = (const float*)d_in[10];
  const float* b1        = (const float*)d_in[11];
  const float* w2        = (const float*)d_in[12];
  const float* b2        = (const float*)d_in[13];

  char* ws = (char*)d_ws;
  bf16_t* nqh   = (bf16_t*)(ws);                    // 4 MB
  bf16_t* nql   = (bf16_t*)(ws + ((size_t)4<<20));  // 4 MB
  bf16_t* qh    = (bf16_t*)(ws + ((size_t)8<<20));  // 4 MB
  bf16_t* ql    = (bf16_t*)(ws + ((size_t)12<<20)); // 4 MB
  bf16_t* kh    = (bf16_t*)(ws + ((size_t)16<<20)); // 4 MB
  bf16_t* kl    = (bf16_t*)(ws + ((size_t)20<<20)); // 4 MB
  bf16_t* vtmp  = (bf16_t*)(ws + ((size_t)24<<20)); // 4 MB
  bf16_t* vt    = (bf16_t*)(ws + ((size_t)28<<20)); // 4 MB
  bf16_t* og    = (bf16_t*)(ws + ((size_t)32<<20)); // 4 MB
  bf16_t* hmid  = (bf16_t*)(ws + ((size_t)36<<20)); // 4 MB
  bf16_t* h1    = (bf16_t*)(ws + ((size_t)40<<20)); // 16 MB
  bf16_t* wqh   = (bf16_t*)(ws + ((size_t)56<<20)); // 1.5 MB
  bf16_t* wql   = (bf16_t*)(ws + ((size_t)58<<20)); // 1.5 MB
  bf16_t* woutb = (bf16_t*)(ws + ((size_t)60<<20)); // 0.5 MB
  bf16_t* w1b   = (bf16_t*)(ws + ((size_t)61<<20)); // 2 MB
  bf16_t* w2b   = (bf16_t*)(ws + ((size_t)63<<20)); // 2 MB

  float* xout = (float*)d_out;                       // (B,S,E) fp32
  float* aw   = xout + (size_t)2*S_LEN*E_DIM;        // (B,S,S) fp32

  hipMemsetAsync(aw, 0, (size_t)2*S_LEN*S_LEN*sizeof(float), stream);

  cvt_split_kernel<<<768, 256, 0, stream>>>(in_proj_w, wqh, wql, 786432);
  cvt_kernel<<<256, 256, 0, stream>>>(out_w, woutb, 262144);
  cvt_kernel<<<1024,256, 0, stream>>>(w1,    w1b,   1048576);
  cvt_kernel<<<1024,256, 0, stream>>>(w2,    w2b,   1048576);

  // ln1(query) -> split nq
  ln_split_kernel<<<1024, 256, 0, stream>>>(query, ln1_w, ln1_b, nqh, nql);

  // qkv split GEMM: q,k as hi/lo pairs; v plain flat
  gemm_qkv_split<<<768, 256, 0, stream>>>(nqh, nql, wqh, wql, in_proj_b,
                                          qh, ql, kh, kl, vtmp);

  // v -> vt[i][d][t] (raw-reshape pseudo-head transpose)
  vtrans_kernel<<<128, 256, 0, stream>>>(vtmp, vt);

  // fused gated-renorm softmax attention
  attn_kernel<<<2048, 512, 0, stream>>>(qh, ql, kh, kl, vt, gate, og, aw);

  // x = query + og @ out_w^T + out_b   (fp32 -> d_out)
  gemm_kernel<64,1><<<256, 256, 0, stream>>>(og, woutb, out_b,
      4096, 512, 512, (void*)xout, query);

  // hmid = ln2(x)
  ln_kernel<<<1024, 256, 0, stream>>>(xout, ln2_w, ln2_b, hmid);

  // h1 = gelu(hmid @ w1^T + b1)
  gemm_kernel<128,2><<<512, 256, 0, stream>>>(hmid, w1b, b1,
      4096, 2048, 512, (void*)h1, nullptr);

  // x += h1 @ w2^T + b2
  gemm_kernel<64,3><<<256, 256, 0, stream>>>(h1, w2b, b2,
      4096, 512, 2048, (void*)xout, nullptr);
}

// Round 3
// 825.614 us; speedup vs baseline: 1.0208x; 1.0208x over previous
//
#include <hip/hip_runtime.h>
#include <cstdint>
#include <cstddef>

typedef __bf16 bf16_t;
typedef __bf16 bf16x8 __attribute__((ext_vector_type(8)));
typedef float  f32x4  __attribute__((ext_vector_type(4)));

#define S_LEN   2048
#define E_DIM   512
#define H_NUM   8
#define DH      64
#define MLP_DIM 2048

static __device__ __forceinline__ unsigned short f2bfu(float f){
  bf16_t h = (bf16_t)f;
  return __builtin_bit_cast(unsigned short, h);
}

static __device__ __forceinline__ float gelu_f(float v){
  return 0.5f*v*(1.0f + erff(v*0.70710678118654752f));
}

// ---------------- fp32 -> bf16 convert (plain) ----------------
__global__ __launch_bounds__(256) void cvt_kernel(const float* __restrict__ s,
                                                  bf16_t* __restrict__ d, int n){
  int i = (blockIdx.x*256 + threadIdx.x)*4;
  if (i < n){
    float4 v = *(const float4*)(s + i);
    ushort4 pk;
    pk.x = f2bfu(v.x); pk.y = f2bfu(v.y); pk.z = f2bfu(v.z); pk.w = f2bfu(v.w);
    *(ushort4*)((unsigned short*)d + i) = pk;
  }
}

// ---------------- fp32 -> split (hi+lo) bf16 convert ----------------
__global__ __launch_bounds__(256) void cvt_split_kernel(const float* __restrict__ s,
                                                        bf16_t* __restrict__ dh,
                                                        bf16_t* __restrict__ dl, int n){
  int i = (blockIdx.x*256 + threadIdx.x)*4;
  if (i < n){
    float4 v = *(const float4*)(s + i);
    float xs[4] = {v.x, v.y, v.z, v.w};
    ushort4 ph, pl;
    unsigned short* hp = (unsigned short*)&ph;
    unsigned short* lp = (unsigned short*)&pl;
    #pragma unroll
    for (int j=0;j<4;j++){
      bf16_t hi = (bf16_t)xs[j];
      bf16_t lo = (bf16_t)(xs[j] - (float)hi);
      hp[j] = __builtin_bit_cast(unsigned short, hi);
      lp[j] = __builtin_bit_cast(unsigned short, lo);
    }
    *(ushort4*)((unsigned short*)dh + i) = ph;
    *(ushort4*)((unsigned short*)dl + i) = pl;
  }
}

// ---------------- LayerNorm (plain bf16 out): one wave per row ----------------
__global__ __launch_bounds__(256) void ln_kernel(const float* __restrict__ x,
                                                 const float* __restrict__ w,
                                                 const float* __restrict__ bb,
                                                 bf16_t* __restrict__ out){
  const int row  = blockIdx.x*4 + (threadIdx.x>>6);
  const int lane = threadIdx.x & 63;
  const float* xr = x + (size_t)row*E_DIM + lane*8;
  float4 v0 = *(const float4*)xr;
  float4 v1 = *(const float4*)(xr + 4);
  float xs[8] = {v0.x, v0.y, v0.z, v0.w, v1.x, v1.y, v1.z, v1.w};
  float s = 0.f, s2 = 0.f;
  #pragma unroll
  for (int j=0;j<8;j++){ s += xs[j]; s2 += xs[j]*xs[j]; }
  #pragma unroll
  for (int off=1; off<64; off<<=1){
    s  += __shfl_xor(s,  off, 64);
    s2 += __shfl_xor(s2, off, 64);
  }
  float mean = s*(1.f/512.f);
  float var  = s2*(1.f/512.f) - mean*mean;
  float rstd = rsqrtf(fmaxf(var, 0.f) + 1e-5f);
  const float* wp = w  + lane*8;
  const float* bp = bb + lane*8;
  bf16x8 ov;
  #pragma unroll
  for (int j=0;j<8;j++)
    ov[j] = (bf16_t)((xs[j]-mean)*rstd*wp[j] + bp[j]);
  *(bf16x8*)(out + (size_t)row*E_DIM + lane*8) = ov;
}

// ---------------- LayerNorm with split hi/lo bf16 output ----------------
__global__ __launch_bounds__(256) void ln_split_kernel(const float* __restrict__ x,
                                                       const float* __restrict__ w,
                                                       const float* __restrict__ bb,
                                                       bf16_t* __restrict__ oh,
                                                       bf16_t* __restrict__ ol){
  const int row  = blockIdx.x*4 + (threadIdx.x>>6);
  const int lane = threadIdx.x & 63;
  const float* xr = x + (size_t)row*E_DIM + lane*8;
  float4 v0 = *(const float4*)xr;
  float4 v1 = *(const float4*)(xr + 4);
  float xs[8] = {v0.x, v0.y, v0.z, v0.w, v1.x, v1.y, v1.z, v1.w};
  float s = 0.f, s2 = 0.f;
  #pragma unroll
  for (int j=0;j<8;j++){ s += xs[j]; s2 += xs[j]*xs[j]; }
  #pragma unroll
  for (int off=1; off<64; off<<=1){
    s  += __shfl_xor(s,  off, 64);
    s2 += __shfl_xor(s2, off, 64);
  }
  float mean = s*(1.f/512.f);
  float var  = s2*(1.f/512.f) - mean*mean;
  float rstd = rsqrtf(fmaxf(var, 0.f) + 1e-5f);
  const float* wp = w  + lane*8;
  const float* bp = bb + lane*8;
  bf16x8 vh, vl;
  #pragma unroll
  for (int j=0;j<8;j++){
    float v = (xs[j]-mean)*rstd*wp[j] + bp[j];
    bf16_t hi = (bf16_t)v;
    vh[j] = hi;
    vl[j] = (bf16_t)(v - (float)hi);
  }
  size_t o = (size_t)row*E_DIM + lane*8;
  *(bf16x8*)(oh + o) = vh;
  *(bf16x8*)(ol + o) = vl;
}

// ---------------- split-precision QKV GEMM ----------------
__global__ __launch_bounds__(256) void gemm_qkv_split(
    const bf16_t* __restrict__ Ah, const bf16_t* __restrict__ Al,
    const bf16_t* __restrict__ Bh, const bf16_t* __restrict__ Bl,
    const float* __restrict__ bias,
    bf16_t* __restrict__ qh, bf16_t* __restrict__ ql,
    bf16_t* __restrict__ kh, bf16_t* __restrict__ kl,
    bf16_t* __restrict__ vtmp)
{
  constexpr int TM = 128, TN = 64, BK = 64, MI = 4, NI = 2;
  const int K = 512;

  __shared__ bf16_t Ahs[TM*BK], Als[TM*BK];
  __shared__ bf16_t Bhs[TN*BK], Bls[TN*BK];

  const int tid  = threadIdx.x;
  const int wave = tid>>6, lane = tid&63, quad = lane>>4, l16 = lane&15;
  const int wm = wave>>1, wn = wave&1;

  const int nblk = 1536/TN;
  const int bm = blockIdx.x / nblk;
  const int bn = blockIdx.x % nblk;
  const int m0 = bm*TM, n0 = bn*TN;

  f32x4 acc[MI][NI];
  #pragma unroll
  for (int i=0;i<MI;i++)
    #pragma unroll
    for (int j=0;j<NI;j++)
      acc[i][j] = (f32x4){0.f,0.f,0.f,0.f};

  for (int k0 = 0; k0 < K; k0 += BK){
    bf16x8 avh[4], avl[4], bvh[2], bvl[2];
    #pragma unroll
    for (int i=0;i<4;i++){
      int ga = tid + i*256;
      int row = ga>>3, c8 = (ga&7) ^ (row&7);
      size_t off = (size_t)(m0+row)*K + k0 + c8*8;
      avh[i] = *(const bf16x8*)(Ah + off);
      avl[i] = *(const bf16x8*)(Al + off);
    }
    #pragma unroll
    for (int i=0;i<2;i++){
      int gb = tid + i*256;
      int row = gb>>3, c8 = (gb&7) ^ (row&7);
      size_t off = (size_t)(n0+row)*K + k0 + c8*8;
      bvh[i] = *(const bf16x8*)(Bh + off);
      bvl[i] = *(const bf16x8*)(Bl + off);
    }
    __syncthreads();
    #pragma unroll
    for (int i=0;i<4;i++){
      *(bf16x8*)(Ahs + (size_t)(tid + i*256)*8) = avh[i];
      *(bf16x8*)(Als + (size_t)(tid + i*256)*8) = avl[i];
    }
    #pragma unroll
    for (int i=0;i<2;i++){
      *(bf16x8*)(Bhs + (size_t)(tid + i*256)*8) = bvh[i];
      *(bf16x8*)(Bls + (size_t)(tid + i*256)*8) = bvl[i];
    }
    __syncthreads();
    #pragma unroll
    for (int ks=0;ks<2;ks++){
      bf16x8 afh[MI], afl[MI], bfh[NI], bfl[NI];
      #pragma unroll
      for (int mi=0;mi<MI;mi++){
        int rm = wm*64 + mi*16 + l16;
        size_t sl = (size_t)(rm*8 + ((ks*4+quad) ^ (rm&7)))*8;
        afh[mi] = *(const bf16x8*)(Ahs + sl);
        afl[mi] = *(const bf16x8*)(Als + sl);
      }
      #pragma unroll
      for (int ni=0;ni<NI;ni++){
        int rn = wn*32 + ni*16 + l16;
        size_t sl = (size_t)(rn*8 + ((ks*4+quad) ^ (rn&7)))*8;
        bfh[ni] = *(const bf16x8*)(Bhs + sl);
        bfl[ni] = *(const bf16x8*)(Bls + sl);
      }
      #pragma unroll
      for (int mi=0;mi<MI;mi++)
        #pragma unroll
        for (int ni=0;ni<NI;ni++){
          acc[mi][ni] = __builtin_amdgcn_mfma_f32_16x16x32_bf16(afh[mi], bfh[ni], acc[mi][ni], 0,0,0);
          acc[mi][ni] = __builtin_amdgcn_mfma_f32_16x16x32_bf16(afl[mi], bfh[ni], acc[mi][ni], 0,0,0);
          acc[mi][ni] = __builtin_amdgcn_mfma_f32_16x16x32_bf16(afh[mi], bfl[ni], acc[mi][ni], 0,0,0);
        }
    }
  }

  #pragma unroll
  for (int mi=0;mi<MI;mi++){
    const int grow0 = m0 + wm*64 + mi*16 + quad*4;
    #pragma unroll
    for (int ni=0;ni<NI;ni++){
      const int gcol = n0 + wn*32 + ni*16 + l16;
      const float bvx = bias[gcol];
      if (gcol < 512){
        #pragma unroll
        for (int r=0;r<4;r++){
          float v = acc[mi][ni][r] + bvx;
          size_t idx = (size_t)(grow0+r)*E_DIM + gcol;
          bf16_t hi = (bf16_t)v;
          qh[idx] = hi;
          ql[idx] = (bf16_t)(v - (float)hi);
        }
      } else if (gcol < 1024){
        const int cc = gcol - 512;
        #pragma unroll
        for (int r=0;r<4;r++){
          float v = acc[mi][ni][r] + bvx;
          size_t idx = (size_t)(grow0+r)*E_DIM + cc;
          bf16_t hi = (bf16_t)v;
          kh[idx] = hi;
          kl[idx] = (bf16_t)(v - (float)hi);
        }
      } else {
        const int cc = gcol - 1024;
        #pragma unroll
        for (int r=0;r<4;r++)
          vtmp[(size_t)(grow0+r)*E_DIM + cc] = (bf16_t)(acc[mi][ni][r] + bvx);
      }
    }
  }
}

// ---------------- V transpose: (B,S,E) flat -> vt[i][d][t] ----------------
__global__ __launch_bounds__(256) void vtrans_kernel(const bf16_t* __restrict__ v,
                                                     bf16_t* __restrict__ vt){
  __shared__ bf16_t tile[32*516];
  const int ic = blockIdx.x >> 3;
  const int rg = blockIdx.x & 7;
  const int tid = threadIdx.x;
  const size_t src = ((size_t)ic*256 + rg*32)*E_DIM;
  #pragma unroll
  for (int j=0;j<8;j++){
    int idx = j*2048 + tid*8;
    int row = idx >> 9, col = idx & 511;
    *(bf16x8*)(tile + row*516 + col) = *(const bf16x8*)(v + src + idx);
  }
  __syncthreads();
  #pragma unroll
  for (int j=0;j<8;j++){
    int idx = j*2048 + tid*8;
    int d = idx >> 8;
    int toff = idx & 255;
    int row = toff >> 3;
    bf16x8 o;
    #pragma unroll
    for (int jj=0;jj<8;jj++)
      o[jj] = tile[row*516 + jj*64 + d];
    *(bf16x8*)(vt + ((size_t)ic*64 + d)*S_LEN + rg*256 + toff) = o;
  }
}

// ---------------- plain bf16 GEMM ----------------
template<int TN, int MODE>
__global__ __launch_bounds__(256) void gemm_kernel(
    const bf16_t* __restrict__ A, const bf16_t* __restrict__ Bw,
    const float* __restrict__ bias, int M, int N, int K,
    void* out0, const float* __restrict__ resid)
{
  constexpr int TM = 128;
  constexpr int BK = 64;
  constexpr int MI = 4;
  constexpr int NI = TN/32;
  constexpr int GB = TN/32;

  __shared__ bf16_t As[TM*BK];
  __shared__ bf16_t Bs[TN*BK];

  const int tid  = threadIdx.x;
  const int wave = tid>>6, lane = tid&63, quad = lane>>4, l16 = lane&15;
  const int wm = wave>>1, wn = wave&1;

  const int nblk = N / TN;
  const int bm = blockIdx.x / nblk;
  const int bn = blockIdx.x % nblk;
  const int m0 = bm*TM, n0 = bn*TN;

  f32x4 acc[MI][NI];
  #pragma unroll
  for (int i=0;i<MI;i++)
    #pragma unroll
    for (int j=0;j<NI;j++)
      acc[i][j] = (f32x4){0.f,0.f,0.f,0.f};

  for (int k0 = 0; k0 < K; k0 += BK){
    bf16x8 av[4];
    #pragma unroll
    for (int i=0;i<4;i++){
      int ga = tid + i*256;
      int row = ga>>3, c8 = (ga&7) ^ (row&7);
      av[i] = *(const bf16x8*)(A + (size_t)(m0+row)*K + k0 + c8*8);
    }
    bf16x8 bv[GB];
    #pragma unroll
    for (int i=0;i<GB;i++){
      int gb = tid + i*256;
      int row = gb>>3, c8 = (gb&7) ^ (row&7);
      bv[i] = *(const bf16x8*)(Bw + (size_t)(n0+row)*K + k0 + c8*8);
    }
    __syncthreads();
    #pragma unroll
    for (int i=0;i<4;i++)  *(bf16x8*)(As + (size_t)(tid + i*256)*8) = av[i];
    #pragma unroll
    for (int i=0;i<GB;i++) *(bf16x8*)(Bs + (size_t)(tid + i*256)*8) = bv[i];
    __syncthreads();
    #pragma unroll
    for (int ks=0;ks<2;ks++){
      bf16x8 af[MI], bfr[NI];
      #pragma unroll
      for (int mi=0;mi<MI;mi++){
        int rm = wm*64 + mi*16 + l16;
        af[mi] = *(const bf16x8*)(As + (size_t)(rm*8 + ((ks*4+quad) ^ (rm&7)))*8);
      }
      #pragma unroll
      for (int ni=0;ni<NI;ni++){
        int rn = wn*(TN/2) + ni*16 + l16;
        bfr[ni] = *(const bf16x8*)(Bs + (size_t)(rn*8 + ((ks*4+quad) ^ (rn&7)))*8);
      }
      #pragma unroll
      for (int mi=0;mi<MI;mi++)
        #pragma unroll
        for (int ni=0;ni<NI;ni++)
          acc[mi][ni] = __builtin_amdgcn_mfma_f32_16x16x32_bf16(af[mi], bfr[ni], acc[mi][ni], 0,0,0);
    }
  }

  #pragma unroll
  for (int mi=0;mi<MI;mi++){
    const int grow0 = m0 + wm*64 + mi*16 + quad*4;
    #pragma unroll
    for (int ni=0;ni<NI;ni++){
      const int gcol = n0 + wn*(TN/2) + ni*16 + l16;
      const float bvx = bias[gcol];
      if constexpr (MODE==1){
        float* xo = (float*)out0;
        #pragma unroll
        for (int r=0;r<4;r++){
          size_t idx = (size_t)(grow0+r)*E_DIM + gcol;
          xo[idx] = resid[idx] + acc[mi][ni][r] + bvx;
        }
      } else if constexpr (MODE==2){
        bf16_t* hp = (bf16_t*)out0;
        #pragma unroll
        for (int r=0;r<4;r++)
          hp[(size_t)(grow0+r)*MLP_DIM + gcol] = (bf16_t)gelu_f(acc[mi][ni][r] + bvx);
      } else {
        float* xo = (float*)out0;
        #pragma unroll
        for (int r=0;r<4;r++){
          size_t idx = (size_t)(grow0+r)*E_DIM + gcol;
          xo[idx] = xo[idx] + acc[mi][ni][r] + bvx;
        }
      }
    }
  }
}

// ---------------- fused attention, 1024 threads (16 waves -> 50% occ) ----------------
__global__ __launch_bounds__(1024) void attn_kernel(
    const bf16_t* __restrict__ qhb, const bf16_t* __restrict__ qlb,
    const bf16_t* __restrict__ khb, const bf16_t* __restrict__ klb,
    const bf16_t* __restrict__ vt,  const float* __restrict__ gate,
    bf16_t* __restrict__ og, float* __restrict__ aw)
{
  __shared__ float  u_s[16*2052];      // 131328 B
  __shared__ double red_d[16*16];
  __shared__ float  red_m[2*16*16];
  __shared__ float  osh[16*64];
  __shared__ float  zsh[16];
  __shared__ float  invr_sh[16];
  __shared__ float  msh[16];

  // XCD swizzle: all 8 pseudo-heads of one (b, q-tile) on one XCD (aw locality)
  const int bid = blockIdx.x;
  const int c = bid & 7;
  const int t = bid >> 3;
  const int h = t & 7;
  const int g = t >> 3;
  const int gi = g*8 + c;
  const int b  = gi >> 7;
  const int sqt = gi & 127;
  const int bh = b*H_NUM + h;
  const int sq0 = sqt*16;

  const int tid = threadIdx.x;
  const int wave = tid>>6, lane = tid&63, quad = lane>>4, l16 = lane&15;

  if (tid < 16*64) osh[tid] = 0.f;
  if (tid >= 1008) zsh[tid-1008] = 0.f;

  bf16x8 qah0, qah1, qal0, qal1;
  {
    const size_t qoff = ((size_t)bh*S_LEN + sq0 + l16)*DH + quad*8;
    qah0 = *(const bf16x8*)(qhb + qoff);
    qah1 = *(const bf16x8*)(qhb + qoff + 32);
    qal0 = *(const bf16x8*)(qlb + qoff);
    qal1 = *(const bf16x8*)(qlb + qoff + 32);
  }

  double sums[4] = {0.0,0.0,0.0,0.0};
  float maxs[4], mins[4];
  #pragma unroll
  for (int r=0;r<4;r++){ maxs[r] = -__builtin_inff(); mins[r] = __builtin_inff(); }

  const size_t gate_row = ((size_t)bh*S_LEN + sq0 + quad*4)*S_LEN;

  // ---- pass 1: u = (q.k^T)*gate -> LDS; fp64 row sums; row max/min
  for (int cb = wave; cb < 32; cb += 16){
    #pragma unroll
    for (int nb=0; nb<4; nb++){
      const int col0 = cb*64 + nb*16;
      const size_t koff = ((size_t)bh*S_LEN + col0 + l16)*DH + quad*8;
      bf16x8 khf0 = *(const bf16x8*)(khb + koff);
      bf16x8 khf1 = *(const bf16x8*)(khb + koff + 32);
      bf16x8 klf0 = *(const bf16x8*)(klb + koff);
      bf16x8 klf1 = *(const bf16x8*)(klb + koff + 32);
      const int sk = col0 + l16;
      const float* gp = gate + gate_row + sk;
      float gv[4];
      #pragma unroll
      for (int r=0;r<4;r++) gv[r] = gp[(size_t)r*S_LEN];
      f32x4 acc = (f32x4){0.f,0.f,0.f,0.f};
      acc = __builtin_amdgcn_mfma_f32_16x16x32_bf16(qah0, khf0, acc, 0,0,0);
      acc = __builtin_amdgcn_mfma_f32_16x16x32_bf16(qah1, khf1, acc, 0,0,0);
      acc = __builtin_amdgcn_mfma_f32_16x16x32_bf16(qal0, khf0, acc, 0,0,0);
      acc = __builtin_amdgcn_mfma_f32_16x16x32_bf16(qal1, khf1, acc, 0,0,0);
      acc = __builtin_amdgcn_mfma_f32_16x16x32_bf16(qah0, klf0, acc, 0,0,0);
      acc = __builtin_amdgcn_mfma_f32_16x16x32_bf16(qah1, klf1, acc, 0,0,0);
      #pragma unroll
      for (int r=0;r<4;r++){
        float u = acc[r]*gv[r];
        u_s[(quad*4+r)*2052 + sk] = u;
        sums[r] += (double)u;
        maxs[r] = fmaxf(maxs[r], u);
        mins[r] = fminf(mins[r], u);
      }
    }
  }

  #pragma unroll
  for (int off=1; off<16; off<<=1){
    #pragma unroll
    for (int r=0;r<4;r++){
      sums[r] += __shfl_xor(sums[r], off, 64);
      maxs[r] = fmaxf(maxs[r], __shfl_xor(maxs[r], off, 64));
      mins[r] = fminf(mins[r], __shfl_xor(mins[r], off, 64));
    }
  }
  if (l16 == 0){
    #pragma unroll
    for (int r=0;r<4;r++){
      red_d[wave*16 + quad*4 + r] = sums[r];
      red_m[(0*16 + wave)*16 + quad*4 + r] = maxs[r];
      red_m[(1*16 + wave)*16 + quad*4 + r] = mins[r];
    }
  }
  __syncthreads();
  if (tid < 16){
    double sm = 0.0;
    float mx = -__builtin_inff(), mn = __builtin_inff();
    #pragma unroll
    for (int w=0; w<16; w++){
      sm += red_d[w*16 + tid];
      mx = fmaxf(mx, red_m[(0*16 + w)*16 + tid]);
      mn = fminf(mn, red_m[(1*16 + w)*16 + tid]);
    }
    double rsum = sm + 1e-12;
    float inv = (float)(1.0/rsum);
    invr_sh[tid] = inv;
    msh[tid] = (rsum > 0.0 ? mx : mn) * inv;   // exact max of u*inv -> max e == 1
  }
  __syncthreads();

  // ---- pass 2: e = exp(u*inv - m); z; o = e @ V  (16 waves: nb2 x k-quarter)
  const float inv_r = invr_sh[l16];
  const float m_v   = msh[l16];
  const int nb2 = wave & 3, kh2 = wave >> 2;
  f32x4 oacc = (f32x4){0.f,0.f,0.f,0.f};
  float zp = 0.f;
  const bf16_t* vbase = vt + ((size_t)bh*DH + nb2*16 + l16)*S_LEN;
  const float* urow = &u_s[l16*2052];
  for (int kc = kh2*16; kc < kh2*16 + 16; kc++){
    const int k0 = kc*32 + quad*8;
    float4 u0 = *(const float4*)(urow + k0);
    float4 u1 = *(const float4*)(urow + k0 + 4);
    float e0 = __expf(u0.x*inv_r - m_v);
    float e1 = __expf(u0.y*inv_r - m_v);
    float e2 = __expf(u0.z*inv_r - m_v);
    float e3 = __expf(u0.w*inv_r - m_v);
    float e4 = __expf(u1.x*inv_r - m_v);
    float e5 = __expf(u1.y*inv_r - m_v);
    float e6 = __expf(u1.z*inv_r - m_v);
    float e7 = __expf(u1.w*inv_r - m_v);
    if (nb2 == 0) zp += ((e0+e1)+(e2+e3)) + ((e4+e5)+(e6+e7));
    bf16x8 pa;
    pa[0]=(bf16_t)e0; pa[1]=(bf16_t)e1; pa[2]=(bf16_t)e2; pa[3]=(bf16_t)e3;
    pa[4]=(bf16_t)e4; pa[5]=(bf16_t)e5; pa[6]=(bf16_t)e6; pa[7]=(bf16_t)e7;
    bf16x8 vf = *(const bf16x8*)(vbase + k0);
    oacc = __builtin_amdgcn_mfma_f32_16x16x32_bf16(pa, vf, oacc, 0,0,0);
  }
  if (nb2 == 0){
    zp += __shfl_xor(zp, 16, 64);
    zp += __shfl_xor(zp, 32, 64);
    if (lane < 16) atomicAdd(&zsh[l16], zp);
  }
  #pragma unroll
  for (int r=0;r<4;r++)
    atomicAdd(&osh[(quad*4+r)*64 + nb2*16 + l16], oacc[r]);
  __syncthreads();

  // ---- epilogue: o/z gathered to (B, t, E) layout for out-proj
  const int bq = bh >> 3, hh = bh & 7;
  if (tid < 16*64){
    int r = tid >> 6, d = tid & 63;
    float val = osh[tid] / zsh[r];
    og[((size_t)(bq*S_LEN + sq0 + r))*E_DIM + hh*DH + d] = (bf16_t)val;
  }

  // ---- pass 3: head-mean attention weights (fp32 atomics, 64 lanes/row)
  const int r3 = tid >> 6;
  const float inv3 = invr_sh[r3], m3 = msh[r3];
  const float sc = 0.125f / zsh[r3];
  float* awrow = aw + ((size_t)(bq*S_LEN) + sq0 + r3)*S_LEN;
  const float* ur3 = &u_s[r3*2052];
  for (int col = lane; col < S_LEN; col += 64){
    float e = __expf(ur3[col]*inv3 - m3);
    atomicAdd(&awrow[col], e*sc);
  }
}

// ---------------- launch ----------------
extern "C" void kernel_launch(void* const* d_in, const int* in_sizes, int n_in,
                              void* d_out, int out_size, void* d_ws, size_t ws_size,
                              hipStream_t stream)
{
  const float* query     = (const float*)d_in[0];
  const float* gate      = (const float*)d_in[1];
  const float* in_proj_w = (const float*)d_in[2];
  const float* in_proj_b = (const float*)d_in[3];
  const float* out_w     = (const float*)d_in[4];
  const float* out_b     = (const float*)d_in[5];
  const float* ln1_w     = (const float*)d_in[6];
  const float* ln1_b     = (const float*)d_in[7];
  const float* ln2_w     = (const float*)d_in[8];
  const float* ln2_b     = (const float*)d_in[9];
  const float* w1        = (const float*)d_in[10];
  const float* b1        = (const float*)d_in[11];
  const float* w2        = (const float*)d_in[12];
  const float* b2        = (const float*)d_in[13];

  char* ws = (char*)d_ws;
  bf16_t* nqh   = (bf16_t*)(ws);                    // 4 MB
  bf16_t* nql   = (bf16_t*)(ws + ((size_t)4<<20));  // 4 MB
  bf16_t* qh    = (bf16_t*)(ws + ((size_t)8<<20));  // 4 MB
  bf16_t* ql    = (bf16_t*)(ws + ((size_t)12<<20)); // 4 MB
  bf16_t* kh    = (bf16_t*)(ws + ((size_t)16<<20)); // 4 MB
  bf16_t* kl    = (bf16_t*)(ws + ((size_t)20<<20)); // 4 MB
  bf16_t* vtmp  = (bf16_t*)(ws + ((size_t)24<<20)); // 4 MB
  bf16_t* vt    = (bf16_t*)(ws + ((size_t)28<<20)); // 4 MB
  bf16_t* og    = (bf16_t*)(ws + ((size_t)32<<20)); // 4 MB
  bf16_t* hmid  = (bf16_t*)(ws + ((size_t)36<<20)); // 4 MB
  bf16_t* h1    = (bf16_t*)(ws + ((size_t)40<<20)); // 16 MB
  bf16_t* wqh   = (bf16_t*)(ws + ((size_t)56<<20)); // 1.5 MB
  bf16_t* wql   = (bf16_t*)(ws + ((size_t)58<<20)); // 1.5 MB
  bf16_t* woutb = (bf16_t*)(ws + ((size_t)60<<20)); // 0.5 MB
  bf16_t* w1b   = (bf16_t*)(ws + ((size_t)61<<20)); // 2 MB
  bf16_t* w2b   = (bf16_t*)(ws + ((size_t)63<<20)); // 2 MB

  float* xout = (float*)d_out;                       // (B,S,E) fp32
  float* aw   = xout + (size_t)2*S_LEN*E_DIM;        // (B,S,S) fp32

  hipMemsetAsync(aw, 0, (size_t)2*S_LEN*S_LEN*sizeof(float), stream);

  cvt_split_kernel<<<768, 256, 0, stream>>>(in_proj_w, wqh, wql, 786432);
  cvt_kernel<<<256, 256, 0, stream>>>(out_w, woutb, 262144);
  cvt_kernel<<<1024,256, 0, stream>>>(w1,    w1b,   1048576);
  cvt_kernel<<<1024,256, 0, stream>>>(w2,    w2b,   1048576);

  // ln1(query) -> split nq
  ln_split_kernel<<<1024, 256, 0, stream>>>(query, ln1_w, ln1_b, nqh, nql);

  // qkv split GEMM: q,k as hi/lo pairs; v plain flat
  gemm_qkv_split<<<768, 256, 0, stream>>>(nqh, nql, wqh, wql, in_proj_b,
                                          qh, ql, kh, kl, vtmp);

  // v -> vt[i][d][t] (raw-reshape pseudo-head transpose)
  vtrans_kernel<<<128, 256, 0, stream>>>(vtmp, vt);

  // fused gated-renorm softmax attention (1024 threads: 16 waves/CU)
  attn_kernel<<<2048, 1024, 0, stream>>>(qh, ql, kh, kl, vt, gate, og, aw);

  // x = query + og @ out_w^T + out_b   (fp32 -> d_out)
  gemm_kernel<64,1><<<256, 256, 0, stream>>>(og, woutb, out_b,
      4096, 512, 512, (void*)xout, query);

  // hmid = ln2(x)
  ln_kernel<<<1024, 256, 0, stream>>>(xout, ln2_w, ln2_b, hmid);

  // h1 = gelu(hmid @ w1^T + b1)
  gemm_kernel<128,2><<<512, 256, 0, stream>>>(hmid, w1b, b1,
      4096, 2048, 512, (void*)h1, nullptr);

  // x += h1 @ w2^T + b2
  gemm_kernel<64,3><<<256, 256, 0, stream>>>(h1, w2b, b2,
      4096, 512, 2048, (void*)xout, nullptr);
}

// Round 4
// 746.612 us; speedup vs baseline: 1.1288x; 1.1058x over previous
//
#include <hip/hip_runtime.h>
#include <cstdint>
#include <cstddef>

typedef __bf16 bf16_t;
typedef __bf16 bf16x8 __attribute__((ext_vector_type(8)));
typedef float  f32x4  __attribute__((ext_vector_type(4)));

#define S_LEN   2048
#define E_DIM   512
#define H_NUM   8
#define DH      64
#define MLP_DIM 2048

static __device__ __forceinline__ unsigned short f2bfu(float f){
  bf16_t h = (bf16_t)f;
  return __builtin_bit_cast(unsigned short, h);
}

static __device__ __forceinline__ float gelu_f(float v){
  return 0.5f*v*(1.0f + erff(v*0.70710678118654752f));
}

// ---------------- fp32 -> bf16 convert (plain) ----------------
__global__ __launch_bounds__(256) void cvt_kernel(const float* __restrict__ s,
                                                  bf16_t* __restrict__ d, int n){
  int i = (blockIdx.x*256 + threadIdx.x)*4;
  if (i < n){
    float4 v = *(const float4*)(s + i);
    ushort4 pk;
    pk.x = f2bfu(v.x); pk.y = f2bfu(v.y); pk.z = f2bfu(v.z); pk.w = f2bfu(v.w);
    *(ushort4*)((unsigned short*)d + i) = pk;
  }
}

// ---------------- fp32 -> split (hi+lo) bf16 convert ----------------
__global__ __launch_bounds__(256) void cvt_split_kernel(const float* __restrict__ s,
                                                        bf16_t* __restrict__ dh,
                                                        bf16_t* __restrict__ dl, int n){
  int i = (blockIdx.x*256 + threadIdx.x)*4;
  if (i < n){
    float4 v = *(const float4*)(s + i);
    float xs[4] = {v.x, v.y, v.z, v.w};
    ushort4 ph, pl;
    unsigned short* hp = (unsigned short*)&ph;
    unsigned short* lp = (unsigned short*)&pl;
    #pragma unroll
    for (int j=0;j<4;j++){
      bf16_t hi = (bf16_t)xs[j];
      bf16_t lo = (bf16_t)(xs[j] - (float)hi);
      hp[j] = __builtin_bit_cast(unsigned short, hi);
      lp[j] = __builtin_bit_cast(unsigned short, lo);
    }
    *(ushort4*)((unsigned short*)dh + i) = ph;
    *(ushort4*)((unsigned short*)dl + i) = pl;
  }
}

// ---------------- LayerNorm (plain bf16 out): one wave per row ----------------
__global__ __launch_bounds__(256) void ln_kernel(const float* __restrict__ x,
                                                 const float* __restrict__ w,
                                                 const float* __restrict__ bb,
                                                 bf16_t* __restrict__ out){
  const int row  = blockIdx.x*4 + (threadIdx.x>>6);
  const int lane = threadIdx.x & 63;
  const float* xr = x + (size_t)row*E_DIM + lane*8;
  float4 v0 = *(const float4*)xr;
  float4 v1 = *(const float4*)(xr + 4);
  float xs[8] = {v0.x, v0.y, v0.z, v0.w, v1.x, v1.y, v1.z, v1.w};
  float s = 0.f, s2 = 0.f;
  #pragma unroll
  for (int j=0;j<8;j++){ s += xs[j]; s2 += xs[j]*xs[j]; }
  #pragma unroll
  for (int off=1; off<64; off<<=1){
    s  += __shfl_xor(s,  off, 64);
    s2 += __shfl_xor(s2, off, 64);
  }
  float mean = s*(1.f/512.f);
  float var  = s2*(1.f/512.f) - mean*mean;
  float rstd = rsqrtf(fmaxf(var, 0.f) + 1e-5f);
  const float* wp = w  + lane*8;
  const float* bp = bb + lane*8;
  bf16x8 ov;
  #pragma unroll
  for (int j=0;j<8;j++)
    ov[j] = (bf16_t)((xs[j]-mean)*rstd*wp[j] + bp[j]);
  *(bf16x8*)(out + (size_t)row*E_DIM + lane*8) = ov;
}

// ---------------- LayerNorm with split hi/lo bf16 output ----------------
__global__ __launch_bounds__(256) void ln_split_kernel(const float* __restrict__ x,
                                                       const float* __restrict__ w,
                                                       const float* __restrict__ bb,
                                                       bf16_t* __restrict__ oh,
                                                       bf16_t* __restrict__ ol){
  const int row  = blockIdx.x*4 + (threadIdx.x>>6);
  const int lane = threadIdx.x & 63;
  const float* xr = x + (size_t)row*E_DIM + lane*8;
  float4 v0 = *(const float4*)xr;
  float4 v1 = *(const float4*)(xr + 4);
  float xs[8] = {v0.x, v0.y, v0.z, v0.w, v1.x, v1.y, v1.z, v1.w};
  float s = 0.f, s2 = 0.f;
  #pragma unroll
  for (int j=0;j<8;j++){ s += xs[j]; s2 += xs[j]*xs[j]; }
  #pragma unroll
  for (int off=1; off<64; off<<=1){
    s  += __shfl_xor(s,  off, 64);
    s2 += __shfl_xor(s2, off, 64);
  }
  float mean = s*(1.f/512.f);
  float var  = s2*(1.f/512.f) - mean*mean;
  float rstd = rsqrtf(fmaxf(var, 0.f) + 1e-5f);
  const float* wp = w  + lane*8;
  const float* bp = bb + lane*8;
  bf16x8 vh, vl;
  #pragma unroll
  for (int j=0;j<8;j++){
    float v = (xs[j]-mean)*rstd*wp[j] + bp[j];
    bf16_t hi = (bf16_t)v;
    vh[j] = hi;
    vl[j] = (bf16_t)(v - (float)hi);
  }
  size_t o = (size_t)row*E_DIM + lane*8;
  *(bf16x8*)(oh + o) = vh;
  *(bf16x8*)(ol + o) = vl;
}

// ---------------- split-precision QKV GEMM ----------------
__global__ __launch_bounds__(256) void gemm_qkv_split(
    const bf16_t* __restrict__ Ah, const bf16_t* __restrict__ Al,
    const bf16_t* __restrict__ Bh, const bf16_t* __restrict__ Bl,
    const float* __restrict__ bias,
    bf16_t* __restrict__ qh, bf16_t* __restrict__ ql,
    bf16_t* __restrict__ kh, bf16_t* __restrict__ kl,
    bf16_t* __restrict__ vtmp)
{
  constexpr int TM = 128, TN = 64, BK = 64, MI = 4, NI = 2;
  const int K = 512;

  __shared__ bf16_t Ahs[TM*BK], Als[TM*BK];
  __shared__ bf16_t Bhs[TN*BK], Bls[TN*BK];

  const int tid  = threadIdx.x;
  const int wave = tid>>6, lane = tid&63, quad = lane>>4, l16 = lane&15;
  const int wm = wave>>1, wn = wave&1;

  const int nblk = 1536/TN;
  const int bm = blockIdx.x / nblk;
  const int bn = blockIdx.x % nblk;
  const int m0 = bm*TM, n0 = bn*TN;

  f32x4 acc[MI][NI];
  #pragma unroll
  for (int i=0;i<MI;i++)
    #pragma unroll
    for (int j=0;j<NI;j++)
      acc[i][j] = (f32x4){0.f,0.f,0.f,0.f};

  for (int k0 = 0; k0 < K; k0 += BK){
    bf16x8 avh[4], avl[4], bvh[2], bvl[2];
    #pragma unroll
    for (int i=0;i<4;i++){
      int ga = tid + i*256;
      int row = ga>>3, c8 = (ga&7) ^ (row&7);
      size_t off = (size_t)(m0+row)*K + k0 + c8*8;
      avh[i] = *(const bf16x8*)(Ah + off);
      avl[i] = *(const bf16x8*)(Al + off);
    }
    #pragma unroll
    for (int i=0;i<2;i++){
      int gb = tid + i*256;
      int row = gb>>3, c8 = (gb&7) ^ (row&7);
      size_t off = (size_t)(n0+row)*K + k0 + c8*8;
      bvh[i] = *(const bf16x8*)(Bh + off);
      bvl[i] = *(const bf16x8*)(Bl + off);
    }
    __syncthreads();
    #pragma unroll
    for (int i=0;i<4;i++){
      *(bf16x8*)(Ahs + (size_t)(tid + i*256)*8) = avh[i];
      *(bf16x8*)(Als + (size_t)(tid + i*256)*8) = avl[i];
    }
    #pragma unroll
    for (int i=0;i<2;i++){
      *(bf16x8*)(Bhs + (size_t)(tid + i*256)*8) = bvh[i];
      *(bf16x8*)(Bls + (size_t)(tid + i*256)*8) = bvl[i];
    }
    __syncthreads();
    #pragma unroll
    for (int ks=0;ks<2;ks++){
      bf16x8 afh[MI], afl[MI], bfh[NI], bfl[NI];
      #pragma unroll
      for (int mi=0;mi<MI;mi++){
        int rm = wm*64 + mi*16 + l16;
        size_t sl = (size_t)(rm*8 + ((ks*4+quad) ^ (rm&7)))*8;
        afh[mi] = *(const bf16x8*)(Ahs + sl);
        afl[mi] = *(const bf16x8*)(Als + sl);
      }
      #pragma unroll
      for (int ni=0;ni<NI;ni++){
        int rn = wn*32 + ni*16 + l16;
        size_t sl = (size_t)(rn*8 + ((ks*4+quad) ^ (rn&7)))*8;
        bfh[ni] = *(const bf16x8*)(Bhs + sl);
        bfl[ni] = *(const bf16x8*)(Bls + sl);
      }
      #pragma unroll
      for (int mi=0;mi<MI;mi++)
        #pragma unroll
        for (int ni=0;ni<NI;ni++){
          acc[mi][ni] = __builtin_amdgcn_mfma_f32_16x16x32_bf16(afh[mi], bfh[ni], acc[mi][ni], 0,0,0);
          acc[mi][ni] = __builtin_amdgcn_mfma_f32_16x16x32_bf16(afl[mi], bfh[ni], acc[mi][ni], 0,0,0);
          acc[mi][ni] = __builtin_amdgcn_mfma_f32_16x16x32_bf16(afh[mi], bfl[ni], acc[mi][ni], 0,0,0);
        }
    }
  }

  #pragma unroll
  for (int mi=0;mi<MI;mi++){
    const int grow0 = m0 + wm*64 + mi*16 + quad*4;
    #pragma unroll
    for (int ni=0;ni<NI;ni++){
      const int gcol = n0 + wn*32 + ni*16 + l16;
      const float bvx = bias[gcol];
      if (gcol < 512){
        #pragma unroll
        for (int r=0;r<4;r++){
          float v = acc[mi][ni][r] + bvx;
          size_t idx = (size_t)(grow0+r)*E_DIM + gcol;
          bf16_t hi = (bf16_t)v;
          qh[idx] = hi;
          ql[idx] = (bf16_t)(v - (float)hi);
        }
      } else if (gcol < 1024){
        const int cc = gcol - 512;
        #pragma unroll
        for (int r=0;r<4;r++){
          float v = acc[mi][ni][r] + bvx;
          size_t idx = (size_t)(grow0+r)*E_DIM + cc;
          bf16_t hi = (bf16_t)v;
          kh[idx] = hi;
          kl[idx] = (bf16_t)(v - (float)hi);
        }
      } else {
        const int cc = gcol - 1024;
        #pragma unroll
        for (int r=0;r<4;r++)
          vtmp[(size_t)(grow0+r)*E_DIM + cc] = (bf16_t)(acc[mi][ni][r] + bvx);
      }
    }
  }
}

// ---------------- V transpose: (B,S,E) flat -> vt[i][d][t] ----------------
__global__ __launch_bounds__(256) void vtrans_kernel(const bf16_t* __restrict__ v,
                                                     bf16_t* __restrict__ vt){
  __shared__ bf16_t tile[32*516];
  const int ic = blockIdx.x >> 3;
  const int rg = blockIdx.x & 7;
  const int tid = threadIdx.x;
  const size_t src = ((size_t)ic*256 + rg*32)*E_DIM;
  #pragma unroll
  for (int j=0;j<8;j++){
    int idx = j*2048 + tid*8;
    int row = idx >> 9, col = idx & 511;
    *(bf16x8*)(tile + row*516 + col) = *(const bf16x8*)(v + src + idx);
  }
  __syncthreads();
  #pragma unroll
  for (int j=0;j<8;j++){
    int idx = j*2048 + tid*8;
    int d = idx >> 8;
    int toff = idx & 255;
    int row = toff >> 3;
    bf16x8 o;
    #pragma unroll
    for (int jj=0;jj<8;jj++)
      o[jj] = tile[row*516 + jj*64 + d];
    *(bf16x8*)(vt + ((size_t)ic*64 + d)*S_LEN + rg*256 + toff) = o;
  }
}

// ---------------- plain bf16 GEMM ----------------
template<int TN, int MODE>
__global__ __launch_bounds__(256) void gemm_kernel(
    const bf16_t* __restrict__ A, const bf16_t* __restrict__ Bw,
    const float* __restrict__ bias, int M, int N, int K,
    void* out0, const float* __restrict__ resid)
{
  constexpr int TM = 128;
  constexpr int BK = 64;
  constexpr int MI = 4;
  constexpr int NI = TN/32;
  constexpr int GB = TN/32;

  __shared__ bf16_t As[TM*BK];
  __shared__ bf16_t Bs[TN*BK];

  const int tid  = threadIdx.x;
  const int wave = tid>>6, lane = tid&63, quad = lane>>4, l16 = lane&15;
  const int wm = wave>>1, wn = wave&1;

  const int nblk = N / TN;
  const int bm = blockIdx.x / nblk;
  const int bn = blockIdx.x % nblk;
  const int m0 = bm*TM, n0 = bn*TN;

  f32x4 acc[MI][NI];
  #pragma unroll
  for (int i=0;i<MI;i++)
    #pragma unroll
    for (int j=0;j<NI;j++)
      acc[i][j] = (f32x4){0.f,0.f,0.f,0.f};

  for (int k0 = 0; k0 < K; k0 += BK){
    bf16x8 av[4];
    #pragma unroll
    for (int i=0;i<4;i++){
      int ga = tid + i*256;
      int row = ga>>3, c8 = (ga&7) ^ (row&7);
      av[i] = *(const bf16x8*)(A + (size_t)(m0+row)*K + k0 + c8*8);
    }
    bf16x8 bv[GB];
    #pragma unroll
    for (int i=0;i<GB;i++){
      int gb = tid + i*256;
      int row = gb>>3, c8 = (gb&7) ^ (row&7);
      bv[i] = *(const bf16x8*)(Bw + (size_t)(n0+row)*K + k0 + c8*8);
    }
    __syncthreads();
    #pragma unroll
    for (int i=0;i<4;i++)  *(bf16x8*)(As + (size_t)(tid + i*256)*8) = av[i];
    #pragma unroll
    for (int i=0;i<GB;i++) *(bf16x8*)(Bs + (size_t)(tid + i*256)*8) = bv[i];
    __syncthreads();
    #pragma unroll
    for (int ks=0;ks<2;ks++){
      bf16x8 af[MI], bfr[NI];
      #pragma unroll
      for (int mi=0;mi<MI;mi++){
        int rm = wm*64 + mi*16 + l16;
        af[mi] = *(const bf16x8*)(As + (size_t)(rm*8 + ((ks*4+quad) ^ (rm&7)))*8);
      }
      #pragma unroll
      for (int ni=0;ni<NI;ni++){
        int rn = wn*(TN/2) + ni*16 + l16;
        bfr[ni] = *(const bf16x8*)(Bs + (size_t)(rn*8 + ((ks*4+quad) ^ (rn&7)))*8);
      }
      #pragma unroll
      for (int mi=0;mi<MI;mi++)
        #pragma unroll
        for (int ni=0;ni<NI;ni++)
          acc[mi][ni] = __builtin_amdgcn_mfma_f32_16x16x32_bf16(af[mi], bfr[ni], acc[mi][ni], 0,0,0);
    }
  }

  #pragma unroll
  for (int mi=0;mi<MI;mi++){
    const int grow0 = m0 + wm*64 + mi*16 + quad*4;
    #pragma unroll
    for (int ni=0;ni<NI;ni++){
      const int gcol = n0 + wn*(TN/2) + ni*16 + l16;
      const float bvx = bias[gcol];
      if constexpr (MODE==1){
        float* xo = (float*)out0;
        #pragma unroll
        for (int r=0;r<4;r++){
          size_t idx = (size_t)(grow0+r)*E_DIM + gcol;
          xo[idx] = resid[idx] + acc[mi][ni][r] + bvx;
        }
      } else if constexpr (MODE==2){
        bf16_t* hp = (bf16_t*)out0;
        #pragma unroll
        for (int r=0;r<4;r++)
          hp[(size_t)(grow0+r)*MLP_DIM + gcol] = (bf16_t)gelu_f(acc[mi][ni][r] + bvx);
      } else {
        float* xo = (float*)out0;
        #pragma unroll
        for (int r=0;r<4;r++){
          size_t idx = (size_t)(grow0+r)*E_DIM + gcol;
          xo[idx] = xo[idx] + acc[mi][ni][r] + bvx;
        }
      }
    }
  }
}

// ---------------- fused attention: one block = (b, 16 q-rows), loops 8 heads ----------------
// aw head-mean accumulated in 32 VGPRs/thread -> single coalesced store. NO global atomics.
__global__ __launch_bounds__(1024) void attn_kernel(
    const bf16_t* __restrict__ qhb, const bf16_t* __restrict__ qlb,
    const bf16_t* __restrict__ khb, const bf16_t* __restrict__ klb,
    const bf16_t* __restrict__ vt,  const float* __restrict__ gate,
    bf16_t* __restrict__ og, float* __restrict__ aw)
{
  __shared__ float  u_s[16*2052];      // 131328 B
  __shared__ double red_d[16*16];
  __shared__ float  red_m[2*16*16];
  __shared__ float  osh[16*64];
  __shared__ float  zsh[16];
  __shared__ float  invr_sh[16];
  __shared__ float  msh[16];

  const int b   = blockIdx.x >> 7;
  const int sqt = blockIdx.x & 127;
  const int sq0 = sqt*16;

  const int tid = threadIdx.x;
  const int wave = tid>>6, lane = tid&63, quad = lane>>4, l16 = lane&15;
  const int row16 = tid >> 6;          // [0,16): aw row owned by this thread

  float awacc[32];
  #pragma unroll
  for (int j=0;j<32;j++) awacc[j] = 0.f;

  for (int h = 0; h < H_NUM; h++){
    const int bh = b*H_NUM + h;

    osh[tid & 1023] = 0.f;
    if (tid < 16) zsh[tid] = 0.f;

    bf16x8 qah0, qah1, qal0, qal1;
    {
      const size_t qoff = ((size_t)bh*S_LEN + sq0 + l16)*DH + quad*8;
      qah0 = *(const bf16x8*)(qhb + qoff);
      qah1 = *(const bf16x8*)(qhb + qoff + 32);
      qal0 = *(const bf16x8*)(qlb + qoff);
      qal1 = *(const bf16x8*)(qlb + qoff + 32);
    }

    double sums[4] = {0.0,0.0,0.0,0.0};
    float maxs[4], mins[4];
    #pragma unroll
    for (int r=0;r<4;r++){ maxs[r] = -__builtin_inff(); mins[r] = __builtin_inff(); }

    const size_t gate_row = ((size_t)bh*S_LEN + sq0 + quad*4)*S_LEN;

    // ---- pass 1: u = (q.k^T)*gate -> LDS; fp64 row sums; row max/min
    for (int cb = wave; cb < 32; cb += 16){
      #pragma unroll
      for (int nb=0; nb<4; nb++){
        const int col0 = cb*64 + nb*16;
        const size_t koff = ((size_t)bh*S_LEN + col0 + l16)*DH + quad*8;
        bf16x8 khf0 = *(const bf16x8*)(khb + koff);
        bf16x8 khf1 = *(const bf16x8*)(khb + koff + 32);
        bf16x8 klf0 = *(const bf16x8*)(klb + koff);
        bf16x8 klf1 = *(const bf16x8*)(klb + koff + 32);
        const int sk = col0 + l16;
        const float* gp = gate + gate_row + sk;
        float gv[4];
        #pragma unroll
        for (int r=0;r<4;r++) gv[r] = __builtin_nontemporal_load(gp + (size_t)r*S_LEN);
        f32x4 acc = (f32x4){0.f,0.f,0.f,0.f};
        acc = __builtin_amdgcn_mfma_f32_16x16x32_bf16(qah0, khf0, acc, 0,0,0);
        acc = __builtin_amdgcn_mfma_f32_16x16x32_bf16(qah1, khf1, acc, 0,0,0);
        acc = __builtin_amdgcn_mfma_f32_16x16x32_bf16(qal0, khf0, acc, 0,0,0);
        acc = __builtin_amdgcn_mfma_f32_16x16x32_bf16(qal1, khf1, acc, 0,0,0);
        acc = __builtin_amdgcn_mfma_f32_16x16x32_bf16(qah0, klf0, acc, 0,0,0);
        acc = __builtin_amdgcn_mfma_f32_16x16x32_bf16(qah1, klf1, acc, 0,0,0);
        #pragma unroll
        for (int r=0;r<4;r++){
          float u = acc[r]*gv[r];
          u_s[(quad*4+r)*2052 + sk] = u;
          sums[r] += (double)u;
          maxs[r] = fmaxf(maxs[r], u);
          mins[r] = fminf(mins[r], u);
        }
      }
    }

    #pragma unroll
    for (int off=1; off<16; off<<=1){
      #pragma unroll
      for (int r=0;r<4;r++){
        sums[r] += __shfl_xor(sums[r], off, 64);
        maxs[r] = fmaxf(maxs[r], __shfl_xor(maxs[r], off, 64));
        mins[r] = fminf(mins[r], __shfl_xor(mins[r], off, 64));
      }
    }
    if (l16 == 0){
      #pragma unroll
      for (int r=0;r<4;r++){
        red_d[wave*16 + quad*4 + r] = sums[r];
        red_m[(0*16 + wave)*16 + quad*4 + r] = maxs[r];
        red_m[(1*16 + wave)*16 + quad*4 + r] = mins[r];
      }
    }
    __syncthreads();
    if (tid < 16){
      double sm = 0.0;
      float mx = -__builtin_inff(), mn = __builtin_inff();
      #pragma unroll
      for (int w=0; w<16; w++){
        sm += red_d[w*16 + tid];
        mx = fmaxf(mx, red_m[(0*16 + w)*16 + tid]);
        mn = fminf(mn, red_m[(1*16 + w)*16 + tid]);
      }
      double rsum = sm + 1e-12;
      float inv = (float)(1.0/rsum);
      invr_sh[tid] = inv;
      msh[tid] = (rsum > 0.0 ? mx : mn) * inv;   // exact max of u*inv -> max e == 1
    }
    __syncthreads();

    // ---- pass 2: e = exp(u*inv - m); z; o = e @ V  (16 waves: nb2 x k-quarter)
    const float inv_r = invr_sh[l16];
    const float m_v   = msh[l16];
    const int nb2 = wave & 3, kh2 = wave >> 2;
    f32x4 oacc = (f32x4){0.f,0.f,0.f,0.f};
    float zp = 0.f;
    const bf16_t* vbase = vt + ((size_t)bh*DH + nb2*16 + l16)*S_LEN;
    const float* urow = &u_s[l16*2052];
    for (int kc = kh2*16; kc < kh2*16 + 16; kc++){
      const int k0 = kc*32 + quad*8;
      float4 u0 = *(const float4*)(urow + k0);
      float4 u1 = *(const float4*)(urow + k0 + 4);
      float e0 = __expf(u0.x*inv_r - m_v);
      float e1 = __expf(u0.y*inv_r - m_v);
      float e2 = __expf(u0.z*inv_r - m_v);
      float e3 = __expf(u0.w*inv_r - m_v);
      float e4 = __expf(u1.x*inv_r - m_v);
      float e5 = __expf(u1.y*inv_r - m_v);
      float e6 = __expf(u1.z*inv_r - m_v);
      float e7 = __expf(u1.w*inv_r - m_v);
      if (nb2 == 0) zp += ((e0+e1)+(e2+e3)) + ((e4+e5)+(e6+e7));
      bf16x8 pa;
      pa[0]=(bf16_t)e0; pa[1]=(bf16_t)e1; pa[2]=(bf16_t)e2; pa[3]=(bf16_t)e3;
      pa[4]=(bf16_t)e4; pa[5]=(bf16_t)e5; pa[6]=(bf16_t)e6; pa[7]=(bf16_t)e7;
      bf16x8 vf = *(const bf16x8*)(vbase + k0);
      oacc = __builtin_amdgcn_mfma_f32_16x16x32_bf16(pa, vf, oacc, 0,0,0);
    }
    if (nb2 == 0){
      zp += __shfl_xor(zp, 16, 64);
      zp += __shfl_xor(zp, 32, 64);
      if (lane < 16) atomicAdd(&zsh[l16], zp);
    }
    #pragma unroll
    for (int r=0;r<4;r++)
      atomicAdd(&osh[(quad*4+r)*64 + nb2*16 + l16], oacc[r]);
    __syncthreads();

    // ---- epilogue: o/z gathered to (B, t, E) layout for out-proj
    {
      int r = tid >> 6, d = tid & 63;
      float val = osh[tid] / zsh[r];
      og[((size_t)(b*S_LEN + sq0 + r))*E_DIM + h*DH + d] = (bf16_t)val;
    }

    // ---- pass 3: accumulate head-mean attention weights in registers
    {
      const float inv3 = invr_sh[row16], m3 = msh[row16];
      const float sc = 0.125f / zsh[row16];
      const float* ur = &u_s[row16*2052];
      #pragma unroll
      for (int j=0;j<32;j++){
        float e = __expf(ur[j*64 + lane]*inv3 - m3);
        awacc[j] = fmaf(e, sc, awacc[j]);
      }
    }
    __syncthreads();   // protect u_s / osh / zsh / invr / msh for next head
  }

  // ---- single coalesced aw write (no atomics, no memset needed)
  float* awrow = aw + ((size_t)(b*S_LEN) + sq0 + row16)*S_LEN;
  #pragma unroll
  for (int j=0;j<32;j++)
    __builtin_nontemporal_store(awacc[j], awrow + j*64 + lane);
}

// ---------------- launch ----------------
extern "C" void kernel_launch(void* const* d_in, const int* in_sizes, int n_in,
                              void* d_out, int out_size, void* d_ws, size_t ws_size,
                              hipStream_t stream)
{
  const float* query     = (const float*)d_in[0];
  const float* gate      = (const float*)d_in[1];
  const float* in_proj_w = (const float*)d_in[2];
  const float* in_proj_b = (const float*)d_in[3];
  const float* out_w     = (const float*)d_in[4];
  const float* out_b     = (const float*)d_in[5];
  const float* ln1_w     = (const float*)d_in[6];
  const float* ln1_b     = (const float*)d_in[7];
  const float* ln2_w     = (const float*)d_in[8];
  const float* ln2_b     = (const float*)d_in[9];
  const float* w1        = (const float*)d_in[10];
  const float* b1        = (const float*)d_in[11];
  const float* w2        = (const float*)d_in[12];
  const float* b2        = (const float*)d_in[13];

  char* ws = (char*)d_ws;
  bf16_t* nqh   = (bf16_t*)(ws);                    // 4 MB
  bf16_t* nql   = (bf16_t*)(ws + ((size_t)4<<20));  // 4 MB
  bf16_t* qh    = (bf16_t*)(ws + ((size_t)8<<20));  // 4 MB
  bf16_t* ql    = (bf16_t*)(ws + ((size_t)12<<20)); // 4 MB
  bf16_t* kh    = (bf16_t*)(ws + ((size_t)16<<20)); // 4 MB
  bf16_t* kl    = (bf16_t*)(ws + ((size_t)20<<20)); // 4 MB
  bf16_t* vtmp  = (bf16_t*)(ws + ((size_t)24<<20)); // 4 MB
  bf16_t* vt    = (bf16_t*)(ws + ((size_t)28<<20)); // 4 MB
  bf16_t* og    = (bf16_t*)(ws + ((size_t)32<<20)); // 4 MB
  bf16_t* hmid  = (bf16_t*)(ws + ((size_t)36<<20)); // 4 MB
  bf16_t* h1    = (bf16_t*)(ws + ((size_t)40<<20)); // 16 MB
  bf16_t* wqh   = (bf16_t*)(ws + ((size_t)56<<20)); // 1.5 MB
  bf16_t* wql   = (bf16_t*)(ws + ((size_t)58<<20)); // 1.5 MB
  bf16_t* woutb = (bf16_t*)(ws + ((size_t)60<<20)); // 0.5 MB
  bf16_t* w1b   = (bf16_t*)(ws + ((size_t)61<<20)); // 2 MB
  bf16_t* w2b   = (bf16_t*)(ws + ((size_t)63<<20)); // 2 MB

  float* xout = (float*)d_out;                       // (B,S,E) fp32
  float* aw   = xout + (size_t)2*S_LEN*E_DIM;        // (B,S,S) fp32

  cvt_split_kernel<<<768, 256, 0, stream>>>(in_proj_w, wqh, wql, 786432);
  cvt_kernel<<<256, 256, 0, stream>>>(out_w, woutb, 262144);
  cvt_kernel<<<1024,256, 0, stream>>>(w1,    w1b,   1048576);
  cvt_kernel<<<1024,256, 0, stream>>>(w2,    w2b,   1048576);

  // ln1(query) -> split nq
  ln_split_kernel<<<1024, 256, 0, stream>>>(query, ln1_w, ln1_b, nqh, nql);

  // qkv split GEMM: q,k as hi/lo pairs; v plain flat
  gemm_qkv_split<<<768, 256, 0, stream>>>(nqh, nql, wqh, wql, in_proj_b,
                                          qh, ql, kh, kl, vtmp);

  // v -> vt[i][d][t] (raw-reshape pseudo-head transpose)
  vtrans_kernel<<<128, 256, 0, stream>>>(vtmp, vt);

  // fused gated-renorm softmax attention: 256 blocks, 8 heads/block, no atomics
  attn_kernel<<<256, 1024, 0, stream>>>(qh, ql, kh, kl, vt, gate, og, aw);

  // x = query + og @ out_w^T + out_b   (fp32 -> d_out)
  gemm_kernel<64,1><<<256, 256, 0, stream>>>(og, woutb, out_b,
      4096, 512, 512, (void*)xout, query);

  // hmid = ln2(x)
  ln_kernel<<<1024, 256, 0, stream>>>(xout, ln2_w, ln2_b, hmid);

  // h1 = gelu(hmid @ w1^T + b1)
  gemm_kernel<128,2><<<512, 256, 0, stream>>>(hmid, w1b, b1,
      4096, 2048, 512, (void*)h1, nullptr);

  // x += h1 @ w2^T + b2
  gemm_kernel<64,3><<<256, 256, 0, stream>>>(h1, w2b, b2,
      4096, 512, 2048, (void*)xout, nullptr);
}